// Round 8
// baseline (82.849 us; speedup 1.0000x reference)
//
#include <hip/hip_runtime.h>

// AdaptiveRankingLoss, N=8192, fp32 in / scalar fp32 out.
// mean over pairs (i<j, t_i!=t_j) of hinge(margin - sign(tdiff)*pdiff)/(1+u_i+u_j).
//
// R7 -> R8: i-register blocking IR=4. Wave-tile = 256 i (4 per lane) x 64 j.
// The per-j broadcast (3 v_readlane) now serves 256 pairs instead of 64 --
// broadcast+hazard cost drops ~4x; this was the shared bottleneck of R4 (LDS
// pipe saturated) and R5/R7 (readlane VALU+hazards). Hot tiles (1984/2112)
// have NO positional predicate, only tdiff!=0. Trapezoid decode:
// count(it) = ncj - 4*it, base(it) = it*ncj - 2*it*(it-1).
// Harness floor: 256 MiB d_ws re-poison (~39.4us) + fills/restores not ours.

constexpr int CH  = 64;   // j-chunk = wave width
constexpr int IR  = 4;    // i-values per lane
constexpr int WPB = 4;    // waves per block -> 256 threads

__device__ __forceinline__ float bcastf(float v, int lane) {
    return __int_as_float(__builtin_amdgcn_readlane(__float_as_int(v), lane));
}

__device__ __forceinline__ void pair_math(
    float pi, float ti, float ui1, float tj, float pj, float uj,
    float& h_out, float& w_out, bool& nz_out)
{
    const float tdiff = ti - tj;
    const float pdiff = pi - pj;
    const float m3 = __builtin_amdgcn_fmed3f(fabsf(tdiff), 0.1f, 1.0f);
    const float spd = __uint_as_float(__float_as_uint(pdiff) ^
                                      (__float_as_uint(tdiff) & 0x80000000u));
    h_out  = fmaxf(fmaf(m3, 0.1f, -spd), 0.0f);
    w_out  = __builtin_amdgcn_rcpf(ui1 + uj);   // 1/(1+u_i+u_j)
    nz_out = (tdiff != 0.0f);
}

__global__ __launch_bounds__(CH * WPB) void arl_pair_kernel(
    const float* __restrict__ pred, const float* __restrict__ targ,
    const float* __restrict__ unc, int n, int ncj, int nti, int nTiles,
    float2* __restrict__ partials)
{
    const int tid    = threadIdx.x;
    const int lane   = tid & 63;
    const int wid    = tid >> 6;
    const int tileId = blockIdx.x * WPB + wid;

    float acc[IR] = {0.f, 0.f, 0.f, 0.f};
    unsigned cnt = 0;

    if (tileId < nTiles) {
        // decode trapezoid tile id -> (it, jt), jt in [4*it, ncj)
        const float A = (float)ncj + 2.0f;
        int it = (int)((A - sqrtf(fmaxf(A * A - 8.0f * (float)tileId, 0.0f))) * 0.25f);
        if (it < 0) it = 0;
        if (it > nti - 1) it = nti - 1;
        auto base = [ncj](int r) { return r * ncj - 2 * r * (r - 1); };
        while (it + 1 < nti && base(it + 1) <= tileId) ++it;
        while (it > 0 && base(it) > tileId) --it;
        const int jt = 4 * it + (tileId - base(it));

        const int i0 = it * (CH * IR);     // i-band start (256 i)
        const int j0 = jt * CH;            // j-chunk start (64 j)
        const int jg = j0 + lane;

        const bool hot = (jt >= 4 * it + IR) && (i0 + CH * IR <= n) && (j0 + CH <= n);

        if (hot) {
            float pi[IR], ti[IR], ui1[IR];
            #pragma unroll
            for (int k = 0; k < IR; ++k) {
                const int i = i0 + CH * k + lane;
                pi[k]  = pred[i];
                ti[k]  = targ[i];
                ui1[k] = 1.0f + unc[i];
            }
            const float tjv = targ[jg];    // j-chunk lives in this wave's lanes
            const float pjv = pred[jg];
            const float ujv = unc[jg];

            #pragma unroll 8
            for (int jj = 0; jj < CH; ++jj) {
                const float tj = bcastf(tjv, jj);
                const float pj = bcastf(pjv, jj);
                const float uj = bcastf(ujv, jj);
                #pragma unroll
                for (int k = 0; k < IR; ++k) {
                    float h, w; bool nz;
                    pair_math(pi[k], ti[k], ui1[k], tj, pj, uj, h, w, nz);
                    acc[k] = fmaf(nz ? w : 0.0f, h, acc[k]);
                    cnt += (unsigned)__popcll(__ballot(nz));   // scalar pipe
                }
            }
        } else {
            // generic path: diagonal tiles (jt in [4it, 4it+IR)) and n-edges
            int   dk[IR];
            bool  iv[IR];
            float pi[IR], ti[IR], ui1[IR];
            #pragma unroll
            for (int k = 0; k < IR; ++k) {
                const int i = i0 + CH * k + lane;
                dk[k] = jt - 4 * it - k;
                iv[k] = i < n;
                pi[k]  = iv[k] ? pred[i] : 0.0f;
                ti[k]  = iv[k] ? targ[i] : 0.0f;
                ui1[k] = 1.0f + (iv[k] ? unc[i] : 0.0f);
            }
            const bool jv = jg < n;
            const float tjv = jv ? targ[jg] : 0.0f;
            const float pjv = jv ? pred[jg] : 0.0f;
            const float ujv = jv ? unc[jg] : 0.0f;

            #pragma unroll 4
            for (int jj = 0; jj < CH; ++jj) {
                const bool jok = (j0 + jj) < n;
                const float tj = bcastf(tjv, jj);
                const float pj = bcastf(pjv, jj);
                const float uj = bcastf(ujv, jj);
                #pragma unroll
                for (int k = 0; k < IR; ++k) {
                    float h, w; bool nz;
                    pair_math(pi[k], ti[k], ui1[k], tj, pj, uj, h, w, nz);
                    const bool pos = (dk[k] > 0) || (dk[k] == 0 && lane < jj);
                    const bool use = nz && pos && iv[k] && jok;
                    acc[k] = fmaf(use ? w : 0.0f, h, acc[k]);
                    cnt += (unsigned)__popcll(__ballot(use));
                }
            }
        }
    }

    float acct = (acc[0] + acc[1]) + (acc[2] + acc[3]);
    for (int off = 32; off > 0; off >>= 1) acct += __shfl_down(acct, off);

    __shared__ float sa[WPB], sc[WPB];
    if (lane == 0) { sa[wid] = acct; sc[wid] = (float)cnt; }  // cnt<=16384, exact
    __syncthreads();
    if (tid == 0) {
        float a2 = 0.0f, c2 = 0.0f;
        #pragma unroll
        for (int w = 0; w < WPB; ++w) { a2 += sa[w]; c2 += sc[w]; }
        partials[blockIdx.x] = float2{a2, c2};   // cnt/block <= 65536, exact fp32
    }
}

__global__ __launch_bounds__(256) void arl_finalize(
    const float2* __restrict__ partials, int nPartials, float* __restrict__ out)
{
    float a = 0.0f, c = 0.0f;
    for (int k = threadIdx.x; k < nPartials; k += 256) {
        const float2 v = partials[k];
        a += v.x; c += v.y;
    }
    for (int off = 32; off > 0; off >>= 1) {
        a += __shfl_down(a, off);
        c += __shfl_down(c, off);
    }
    __shared__ float sa[4], sc[4];
    const int lane = threadIdx.x & 63, wid = threadIdx.x >> 6;
    if (lane == 0) { sa[wid] = a; sc[wid] = c; }
    __syncthreads();
    if (threadIdx.x == 0) {
        double A = 0.0, C = 0.0;
        #pragma unroll
        for (int w = 0; w < 4; ++w) { A += (double)sa[w]; C += (double)sc[w]; }
        out[0] = (float)(A / (C > 0.0 ? C : 1.0));
    }
}

extern "C" void kernel_launch(void* const* d_in, const int* in_sizes, int n_in,
                              void* d_out, int out_size, void* d_ws, size_t ws_size,
                              hipStream_t stream) {
    const float* pred = (const float*)d_in[0];
    const float* targ = (const float*)d_in[1];
    const float* unc  = (const float*)d_in[2];
    const int n = in_sizes[0];

    const int nti = (n + CH * IR - 1) / (CH * IR);      // i-bands of 256 (32)
    const int ncj = (n + CH - 1) / CH;                  // j-chunks of 64 (128)
    const int nTiles  = nti * ncj - 2 * nti * (nti - 1); // trapezoid (2112)
    const int nBlocks = (nTiles + WPB - 1) / WPB;        // 528

    float2* partials = (float2*)d_ws;                    // nBlocks float2, all written

    arl_pair_kernel<<<nBlocks, CH * WPB, 0, stream>>>(pred, targ, unc, n, ncj,
                                                      nti, nTiles, partials);
    arl_finalize<<<1, 256, 0, stream>>>(partials, nBlocks, (float*)d_out);
}

// Round 9
// 82.311 us; speedup vs baseline: 1.0065x; 1.0065x over previous
//
#include <hip/hip_runtime.h>

// AdaptiveRankingLoss, N=8192, fp32 in / scalar fp32 out.
// mean over pairs (i<j, t_i!=t_j) of hinge(margin - sign(tdiff)*pdiff)/(1+u_i+u_j).
//
// R8 -> R9: combine the winners. LDS float4 broadcast (hazard-free, beat
// readlane in R4 vs R5/R7/R8) + IR=4 i-register blocking (R8's amortization)
// + block-shared j-staging: block-tile 1024i x 64j, 256 threads, the 64
// staged float4s serve all 4 waves -> one ds_read_b128 per 1024 pairs.
// R8's readlane loop lost to VALU->SGPR hazard s_nops at 2 waves/SIMD.
// Trapezoid: 8 i-bands x 128 j-chunks -> 576 blocks; 448 hot tiles have only
// the tdiff!=0 predicate; diagonal tiles use (dbase+jj)>lane.
// Harness floor: 256 MiB d_ws re-poison (~39.4us) + fills/restores not ours.

constexpr int CH    = 64;              // j-chunk width
constexpr int IR    = 4;               // i-values per lane
constexpr int WPB   = 4;               // waves per block
constexpr int IBAND = CH * IR * WPB;   // 1024 i per block-tile
constexpr int JPB   = IBAND / CH;      // 16 j-chunks per i-band

__global__ __launch_bounds__(CH * WPB) void arl_pair_kernel(
    const float* __restrict__ pred, const float* __restrict__ targ,
    const float* __restrict__ unc, int n, int ncj, int nbi, int nTiles,
    float2* __restrict__ partials)
{
    const int tid  = threadIdx.x;
    const int lane = tid & 63;
    const int wid  = tid >> 6;
    const int k    = blockIdx.x;

    // decode trapezoid tile id -> (ib, jt), jt in [JPB*ib, ncj)
    // base(ib) = ib*ncj - 8*ib*(ib-1), count(ib) = ncj - JPB*ib
    const float A = (float)ncj + 8.0f;
    int ib = (int)((A - sqrtf(fmaxf(A * A - 32.0f * (float)k, 0.0f))) * 0.0625f);
    if (ib < 0) ib = 0;
    if (ib > nbi - 1) ib = nbi - 1;
    auto base = [ncj](int r) { return r * ncj - 8 * r * (r - 1); };
    while (ib + 1 < nbi && base(ib + 1) <= k) ++ib;
    while (ib > 0 && base(ib) > k) --ib;
    const int jt = JPB * ib + (k - base(ib));

    const int i0 = ib * IBAND;
    const int j0 = jt * CH;

    // stage j-chunk in LDS as float4{t,p,u,0} (one ds_read_b128 broadcast/iter)
    __shared__ float4 sj[CH];
    if (tid < CH) {
        const int jg = j0 + tid;
        const bool v = jg < n;
        sj[tid] = make_float4(v ? targ[jg] : 0.0f, v ? pred[jg] : 0.0f,
                              v ? unc[jg] : 0.0f, 0.0f);
    }
    __syncthreads();

    float acc[IR] = {0.f, 0.f, 0.f, 0.f};
    unsigned cnt = 0;

    const bool hot = (jt >= JPB * ib + JPB) && (i0 + IBAND <= n) && (j0 + CH <= n);

    if (hot) {
        float pi[IR], ti[IR], ui1[IR];
        #pragma unroll
        for (int kk = 0; kk < IR; ++kk) {
            const int i = i0 + (wid * IR + kk) * CH + lane;
            pi[kk]  = pred[i];
            ti[kk]  = targ[i];
            ui1[kk] = 1.0f + unc[i];
        }
        #pragma unroll 8
        for (int jj = 0; jj < CH; ++jj) {
            const float4 v = sj[jj];                  // wave-uniform broadcast
            #pragma unroll
            for (int kk = 0; kk < IR; ++kk) {
                const float tdiff = ti[kk] - v.x;
                const float pdiff = pi[kk] - v.y;
                const float m3 = __builtin_amdgcn_fmed3f(fabsf(tdiff), 0.1f, 1.0f);
                const float spd = __uint_as_float(__float_as_uint(pdiff) ^
                                                  (__float_as_uint(tdiff) & 0x80000000u));
                const float h = fmaxf(fmaf(m3, 0.1f, -spd), 0.0f);
                const float w = __builtin_amdgcn_rcpf(ui1[kk] + v.z);
                const bool nz = (tdiff != 0.0f);
                acc[kk] = fmaf(nz ? w : 0.0f, h, acc[kk]);
                cnt += (unsigned)__popcll(__ballot(nz));   // scalar pipe
            }
        }
    } else {
        // diagonal-overlap tiles and n-edges
        bool  iv[IR];
        int   db[IR];
        float pi[IR], ti[IR], ui1[IR];
        #pragma unroll
        for (int kk = 0; kk < IR; ++kk) {
            const int ibase = i0 + (wid * IR + kk) * CH;
            const int i = ibase + lane;
            db[kk] = j0 - ibase;                     // pos iff db+jj > lane
            iv[kk] = i < n;
            pi[kk]  = iv[kk] ? pred[i] : 0.0f;
            ti[kk]  = iv[kk] ? targ[i] : 0.0f;
            ui1[kk] = 1.0f + (iv[kk] ? unc[i] : 0.0f);
        }
        #pragma unroll 4
        for (int jj = 0; jj < CH; ++jj) {
            const float4 v = sj[jj];
            const bool jok = (j0 + jj) < n;
            #pragma unroll
            for (int kk = 0; kk < IR; ++kk) {
                const float tdiff = ti[kk] - v.x;
                const float pdiff = pi[kk] - v.y;
                const float m3 = __builtin_amdgcn_fmed3f(fabsf(tdiff), 0.1f, 1.0f);
                const float spd = __uint_as_float(__float_as_uint(pdiff) ^
                                                  (__float_as_uint(tdiff) & 0x80000000u));
                const float h = fmaxf(fmaf(m3, 0.1f, -spd), 0.0f);
                const float w = __builtin_amdgcn_rcpf(ui1[kk] + v.z);
                const bool use = (tdiff != 0.0f) && ((db[kk] + jj) > lane)
                                 && iv[kk] && jok;
                acc[kk] = fmaf(use ? w : 0.0f, h, acc[kk]);
                cnt += (unsigned)__popcll(__ballot(use));
            }
        }
    }

    float acct = (acc[0] + acc[1]) + (acc[2] + acc[3]);
    for (int off = 32; off > 0; off >>= 1) acct += __shfl_down(acct, off);

    __shared__ float sa[WPB], sc[WPB];
    if (lane == 0) { sa[wid] = acct; sc[wid] = (float)cnt; }  // <=16384/wave, exact
    __syncthreads();
    if (tid == 0) {
        float a2 = 0.0f, c2 = 0.0f;
        #pragma unroll
        for (int w = 0; w < WPB; ++w) { a2 += sa[w]; c2 += sc[w]; }
        partials[blockIdx.x] = float2{a2, c2};   // cnt/block <= 65536, exact fp32
    }
}

__global__ __launch_bounds__(256) void arl_finalize(
    const float2* __restrict__ partials, int nPartials, float* __restrict__ out)
{
    float a = 0.0f, c = 0.0f;
    for (int k = threadIdx.x; k < nPartials; k += 256) {
        const float2 v = partials[k];
        a += v.x; c += v.y;
    }
    for (int off = 32; off > 0; off >>= 1) {
        a += __shfl_down(a, off);
        c += __shfl_down(c, off);
    }
    __shared__ float sa[4], sc[4];
    const int lane = threadIdx.x & 63, wid = threadIdx.x >> 6;
    if (lane == 0) { sa[wid] = a; sc[wid] = c; }
    __syncthreads();
    if (threadIdx.x == 0) {
        double A = 0.0, C = 0.0;
        #pragma unroll
        for (int w = 0; w < 4; ++w) { A += (double)sa[w]; C += (double)sc[w]; }
        out[0] = (float)(A / (C > 0.0 ? C : 1.0));
    }
}

extern "C" void kernel_launch(void* const* d_in, const int* in_sizes, int n_in,
                              void* d_out, int out_size, void* d_ws, size_t ws_size,
                              hipStream_t stream) {
    const float* pred = (const float*)d_in[0];
    const float* targ = (const float*)d_in[1];
    const float* unc  = (const float*)d_in[2];
    const int n = in_sizes[0];

    const int nbi = (n + IBAND - 1) / IBAND;            // i-bands of 1024 (8)
    const int ncj = (n + CH - 1) / CH;                  // j-chunks of 64 (128)
    const int nTiles = nbi * ncj - 8 * nbi * (nbi - 1); // trapezoid (576)

    float2* partials = (float2*)d_ws;                   // nTiles float2, all written

    arl_pair_kernel<<<nTiles, CH * WPB, 0, stream>>>(pred, targ, unc, n, ncj,
                                                     nbi, nTiles, partials);
    arl_finalize<<<1, 256, 0, stream>>>(partials, nTiles, (float*)d_out);
}